// Round 1
// baseline (1504.329 us; speedup 1.0000x reference)
//
#include <hip/hip_runtime.h>

// DA-RNN fused — R9: occupancy generation.
//  * BPB 4 -> 2, grid 512, __launch_bounds__(512,4): LDS/block 130 KB -> ~66.7 KB
//    so TWO independent blocks co-reside per CU (16 waves/CU, was 8). Total VALU
//    work per CU unchanged; the second barrier group fills the ~43% idle issue
//    slots (VALUBusy 57%, Occupancy 23% in R8).
//  * q4 keeps double duty: batch index (guard q4<BPB, wave-uniform) vs
//    column-quarter (bg loop 4->2). Structure otherwise identical to R8.
//  * Workspace layout unchanged (QS = T*NT per batch), need = 104.9 MB.

typedef unsigned int   u32;
typedef unsigned short u16;

#define T_  100
#define C_  32
#define NT  512
#define BPB 2
#define TS  132
#define QS  (T_ * NT)

typedef __attribute__((ext_vector_type(2))) __fp16 h16x2;

#if __has_builtin(__builtin_amdgcn_fdot2)
#define HAVE_FDOT2 1
#else
#define HAVE_FDOT2 0
#endif

__device__ __forceinline__ u32 pkh2(float a, float b) {
#if __has_builtin(__builtin_amdgcn_cvt_pkrtz)
  h16x2 p = __builtin_amdgcn_cvt_pkrtz(a, b);
  return __builtin_bit_cast(u32, p);
#else
  union { __fp16 h[2]; u32 u; } v;
  v.h[0] = (__fp16)a; v.h[1] = (__fp16)b;
  return v.u;
#endif
}
__device__ __forceinline__ void unph(u32 p, float& lo, float& hi) {
  union { u32 u; __fp16 h[2]; } v; v.u = p;
  lo = (float)v.h[0]; hi = (float)v.h[1];
}
__device__ __forceinline__ u16 f2h(float f) {
  union { __fp16 h; u16 u; } v; v.h = (__fp16)f; return v.u;
}
__device__ __forceinline__ float h2f(u16 u) {
  union { u16 u; __fp16 h; } v; v.u = u; return (float)v.h;
}
__device__ __forceinline__ float dot2h(u32 w, u32 x, float acc) {
#if HAVE_FDOT2
  return __builtin_amdgcn_fdot2(__builtin_bit_cast(h16x2, w),
                                __builtin_bit_cast(h16x2, x),
                                acc, false);
#else
  float a, b, c, d;
  unph(w, a, b); unph(x, c, d);
  return fmaf(a, c, fmaf(b, d, acc));
#endif
}

#if __has_builtin(__builtin_amdgcn_rcpf)
__device__ __forceinline__ float rcpf_(float x){ return __builtin_amdgcn_rcpf(x); }
#else
__device__ __forceinline__ float rcpf_(float x){ return 1.0f / x; }
#endif
__device__ __forceinline__ float sigm(float x){ return rcpf_(1.0f + __expf(-x)); }
__device__ __forceinline__ float tanh_(float x){
  return 1.0f - 2.0f * rcpf_(1.0f + __expf(2.0f * x));
}
__device__ __forceinline__ float ptanh(float x){
  x = fminf(1.0f, fmaxf(-1.0f, x));
  float x2 = x * x;
  float p  = fmaf(x2, 0.1333333f, -0.3333333f);
  return x * fmaf(x2, p, 1.0f);
}
__device__ __forceinline__ float wsum(float v){
  #pragma unroll
  for (int o = 32; o; o >>= 1) v += __shfl_xor(v, o, 64);
  return v;
}

// ============================ fast kernel (2 batches/block) =================
__global__ void __launch_bounds__(NT, 4)
darnn4(const float* __restrict__ X,
       const float* __restrict__ eWih, const float* __restrict__ eWhh,
       const float* __restrict__ ebih, const float* __restrict__ ebhh,
       const float* __restrict__ eAw,  const float* __restrict__ eAb,
       const float* __restrict__ dW1,  const float* __restrict__ db1,
       const float* __restrict__ dW2,  const float* __restrict__ db2,
       const float* __restrict__ dWih, const float* __restrict__ dWhh,
       const float* __restrict__ dbih, const float* __restrict__ dbhh,
       const float* __restrict__ fcW,  const float* __restrict__ fcb,
       const float* __restrict__ fcfW, const float* __restrict__ fcfb,
       u16* __restrict__ qws,
       float* __restrict__ out)
{
  // LDS ~66.7 KB -> 2 blocks/CU
  __shared__ __align__(16) u16   sE1[BPB][T_ * TS];  // x_tilde -> E1    52800
  __shared__ __align__(16) float sg[BPB][512];       //                  4096
  __shared__ __align__(16) float sh[BPB][128];       // h/d fp32         1024
  __shared__ __align__(16) float sc[BPB][128];       // c fp32           1024
  __shared__ __align__(16) u16   shp[BPB][128];      // h/d fp16          512
  __shared__ __align__(16) u16   scp[BPB][128];      // c fp16            512
  __shared__ __align__(16) float su[BPB][128];       // u / ctx          1024
  __shared__ __align__(16) float spart[BPB][512];    // partials         4096
  __shared__ __align__(16) float sye[BPB][128];      // ye -> beta       1024
  __shared__ __align__(16) float sw2[128];           //                   512
  __shared__ float sred[16];

  const int tid  = threadIdx.x;
  const int lane = tid & 63;
  const int wv   = tid >> 6;     // 0..7
  const int hh   = tid & 127;
  const int q4   = tid >> 7;     // 0..3 (batch idx when <BPB, else col-quarter)
  const int b0   = blockIdx.x * BPB;

  (void)eAb; (void)db2;          // cancel under softmax shift-invariance

  if (tid < 128) sw2[tid] = dW2[tid];

  // ---------- alpha (no max-sub; h/c terms cancel) + x_tilde ----------
  {
    const float* xp = X + (size_t)(b0 + (q4 & (BPB - 1))) * 12800 + hh;
    if (q4 < BPB) {
      float sval = 0.f;
      #pragma unroll 4
      for (int t = 0; t < T_; ++t) sval += xp[t * 128] * eAw[256 + t];
      float e = __expf(sval);
      float s = wsum(e);
      if (lane == 0) sred[wv] = s;
      // stash e across the barrier via spart (cheap, avoids recompute)
      spart[q4][hh] = e;
    }
    __syncthreads();
    if (q4 < BPB) {
      float e  = spart[q4][hh];
      float al = e * rcpf_(sred[q4 * 2] + sred[q4 * 2 + 1]);
      #pragma unroll 4
      for (int t = 0; t < T_; ++t)
        sE1[q4][t * TS + hh] = f2h(al * xp[t * 128]);
      sh[q4][hh] = 0.f; sc[q4][hh] = 0.f; shp[q4][hh] = 0; scp[q4][hh] = 0;
    }
  }
  __syncthreads();

  // ---------- Q GEMM: Q[b][t][r] = eWih[r,:]·x_tilde  (self-produced) ----
  {
    u32 wq[64];
    const float4* wi = (const float4*)(eWih + (size_t)tid * 128);
    #pragma unroll
    for (int i = 0; i < 32; ++i) {
      float4 v = wi[i];
      wq[2*i]   = pkh2(v.x, v.y);
      wq[2*i+1] = pkh2(v.z, v.w);
    }
    #pragma unroll 1
    for (int bg = 0; bg < BPB; ++bg) {
      u16* qb = qws + (size_t)(b0 + bg) * QS;
      #pragma unroll 1
      for (int t = 0; t < T_; ++t) {
        const uint2* xr = (const uint2*)(&sE1[bg][t * TS]);
        float a0 = 0.f, a1 = 0.f;
        #pragma unroll
        for (int k = 0; k < 16; ++k) {
          uint2 xv = xr[k];
          a0 = dot2h(wq[2*k],   xv.x, a0);
          a1 = dot2h(wq[2*k+1], xv.y, a1);
        }
        qb[t * NT + tid] = f2h(a0 + a1);
      }
    }
  }

  // ---------- encoder (2 barriers/step) ----------
  {
    u32 wpkH[64];
    const float4* wr = (const float4*)(eWhh + (size_t)tid * 128);
    #pragma unroll
    for (int i = 0; i < 32; ++i) {
      float4 v = wr[i];
      wpkH[2*i]   = pkh2(v.x, v.y);
      wpkH[2*i+1] = pkh2(v.z, v.w);
    }
    float biasg = ebih[tid] + ebhh[tid];

    u16 qc[BPB];
    #pragma unroll
    for (int bg = 0; bg < BPB; ++bg)
      qc[bg] = qws[(size_t)(b0 + bg) * QS + tid];

    for (int t = 0; t < T_; ++t) {
      u16 qn[BPB];
      #pragma unroll
      for (int bg = 0; bg < BPB; ++bg)
        qn[bg] = (t + 1 < T_) ? qws[(size_t)(b0 + bg) * QS + (t + 1) * NT + tid]
                              : (u16)0;
      #pragma unroll 1
      for (int bg = 0; bg < BPB; ++bg) {
        const uint4* hr = (const uint4*)(const u32*)shp[bg];
        float a0 = biasg + h2f(qc[bg]), a1 = 0.f, a2 = 0.f, a3 = 0.f;
        #pragma unroll
        for (int k = 0; k < 16; ++k) {
          uint4 hv = hr[k];
          a0 = dot2h(wpkH[4*k+0], hv.x, a0);
          a1 = dot2h(wpkH[4*k+1], hv.y, a1);
          a2 = dot2h(wpkH[4*k+2], hv.z, a2);
          a3 = dot2h(wpkH[4*k+3], hv.w, a3);
        }
        sg[bg][tid] = (a0 + a1) + (a2 + a3);
      }
      __syncthreads();
      if (q4 < BPB) {
        float gi = sigm(sg[q4][hh]);
        float gf = sigm(sg[q4][hh + 128]);
        float gg = tanh_(sg[q4][hh + 256]);
        float go = sigm(sg[q4][hh + 384]);
        float c  = gf * sc[q4][hh] + gi * gg;
        sc[q4][hh] = c;
        float h  = go * tanh_(c);
        sh[q4][hh] = h;
        u16 hb = f2h(h);
        shp[q4][hh] = hb;
        scp[q4][hh] = f2h(c);
        // Xe row t shares Q's slab (Q[t] already consumed; barrier-ordered)
        qws[(size_t)(b0 + q4) * QS + t * NT + hh] = hb;
      }
      __syncthreads();
      #pragma unroll
      for (int bg = 0; bg < BPB; ++bg) qc[bg] = qn[bg];
    }
  }

  // ---------- ye[t] = fcW · Xe[t]  ----------
  if (hh < T_) {
    #pragma unroll 1
    for (int bg = 0; bg < BPB; ++bg) {
      const uint2* xe = (const uint2*)(qws + (size_t)(b0 + bg) * QS
                                       + hh * NT + q4 * 32);
      const float* fw = fcW + q4 * 32;
      float a = 0.f;
      #pragma unroll
      for (int k = 0; k < 8; ++k) {
        uint2 xv = xe[k];
        float l0, l1, l2, l3;
        unph(xv.x, l0, l1); unph(xv.y, l2, l3);
        a += fw[4*k]*l0 + fw[4*k+1]*l1 + fw[4*k+2]*l2 + fw[4*k+3]*l3;
      }
      spart[bg][hh * 4 + q4] = a;
    }
  }
  __syncthreads();
  if (hh < T_ && q4 < BPB) {
    float4 p = ((const float4*)spart[q4])[hh];
    sye[q4][hh] = (p.x + p.y) + (p.z + p.w);
  }
  __syncthreads();

  // ---------- E1[t][h] = dW1[h][256:384]·Xe[t] + db1[h] -> LDS ----------
  {
    u32 wtp[64];
    const float4* w4p = (const float4*)(dW1 + (size_t)hh * 384 + 256);
    #pragma unroll
    for (int i = 0; i < 32; ++i) {
      float4 v = w4p[i];
      wtp[2*i]   = pkh2(v.x, v.y);
      wtp[2*i+1] = pkh2(v.z, v.w);
    }
    float b1v = db1[hh];
    #pragma unroll 1
    for (int bg = 0; bg < BPB; ++bg) {
      #pragma unroll 1
      for (int i = 0; i < 25; ++i) {
        int t = q4 * 25 + i;
        const uint2* xe = (const uint2*)(qws + (size_t)(b0 + bg) * QS + t * NT);
        float a0 = 0.f, a1 = 0.f;
        #pragma unroll
        for (int k = 0; k < 16; ++k) {
          uint2 xv = xe[k];
          a0 = dot2h(wtp[2*k],   xv.x, a0);
          a1 = dot2h(wtp[2*k+1], xv.y, a1);
        }
        sE1[bg][t * TS + hh] = f2h(a0 + a1 + b1v);
      }
    }
  }

  // ---------- decoder weights ----------
  u32 wpkD[64];
  {
    const float4* wr = (const float4*)(dWhh + (size_t)tid * 128);
    #pragma unroll
    for (int i = 0; i < 32; ++i) {
      float4 v = wr[i];
      wpkD[2*i]   = pkh2(v.x, v.y);
      wpkD[2*i+1] = pkh2(v.z, v.w);
    }
  }
  u32 wtpU[32];   // dW1 row hh, z-cols [q4*64, q4*64+64)
  {
    const float4* wu = (const float4*)(dW1 + (size_t)hh * 384 + q4 * 64);
    #pragma unroll
    for (int i = 0; i < 16; ++i) {
      float4 v = wu[i];
      wtpU[2*i]   = pkh2(v.x, v.y);
      wtpU[2*i+1] = pkh2(v.z, v.w);
    }
  }
  float biasD = dbih[tid] + dbhh[tid];
  float wihj  = dWih[tid];
  float fcbv  = fcb[0];
  if (q4 < BPB) {
    sh[q4][hh] = 0.f; sc[q4][hh] = 0.f; shp[q4][hh] = 0; scp[q4][hh] = 0;
  }
  __syncthreads();

  // ---------- decoder (5 barriers/step) ----------
  for (int step = 0; step < T_; ++step) {
    // S0: u partials over z=[d;c] cols q4*64..+64, all batches
    #pragma unroll 1
    for (int bg = 0; bg < BPB; ++bg) {
      const u32* bs = (q4 < 2) ? (const u32*)shp[bg] : (const u32*)scp[bg];
      const uint4* vp = (const uint4*)(bs + (q4 & 1) * 32);
      float a0 = 0.f, a1 = 0.f;
      #pragma unroll
      for (int k = 0; k < 8; ++k) {
        uint4 v = vp[k];
        a0 = dot2h(wtpU[4*k+0], v.x, a0);
        a1 = dot2h(wtpU[4*k+1], v.y, a1);
        a0 = dot2h(wtpU[4*k+2], v.z, a0);
        a1 = dot2h(wtpU[4*k+3], v.w, a1);
      }
      spart[bg][q4 * 128 + hh] = a0 + a1;
    }
    __syncthreads();
    // S1: reduce u
    if (q4 < BPB)
      su[q4][hh] = spart[q4][hh] + spart[q4][128 + hh]
                 + spart[q4][256 + hh] + spart[q4][384 + hh];
    __syncthreads();
    // S2: score partials: thread (t=hh<100, quad q4), 32 h each
    if (hh < T_) {
      #pragma unroll 1
      for (int bg = 0; bg < BPB; ++bg) {
        const uint2*  ep = (const uint2*)(&sE1[bg][hh * TS + q4 * 32]);
        const float4* up = (const float4*)(&su[bg][q4 * 32]);
        const float4* wp = (const float4*)(&sw2[q4 * 32]);
        float acc = 0.f;
        #pragma unroll
        for (int j = 0; j < 8; ++j) {
          uint2  e2 = ep[j];
          float4 u4 = up[j];
          float4 w4 = wp[j];
          float e0, e1, e2f, e3;
          unph(e2.x, e0, e1); unph(e2.y, e2f, e3);
          acc += w4.x * ptanh(e0  + u4.x) + w4.y * ptanh(e1 + u4.y)
               + w4.z * ptanh(e2f + u4.z) + w4.w * ptanh(e3 + u4.w);
        }
        spart[bg][hh * 4 + q4] = acc;
      }
    }
    __syncthreads();
    // S3: softmax over t + y, wave-redundant (no barrier after)
    float yv[BPB];
    #pragma unroll
    for (int bg = 0; bg < BPB; ++bg) {
      float4 p0 = ((const float4*)spart[bg])[lane];
      float e0 = __expf((p0.x + p0.y) + (p0.z + p0.w));
      float es = e0, ys = e0 * sye[bg][lane];
      if (lane < 36) {
        float4 p1 = ((const float4*)spart[bg])[64 + lane];
        float e1 = __expf((p1.x + p1.y) + (p1.z + p1.w));
        es += e1; ys += e1 * sye[bg][64 + lane];
      }
      es = wsum(es); ys = wsum(ys);
      yv[bg] = ys * rcpf_(es) + fcbv;
    }
    // S6: gates
    #pragma unroll 1
    for (int bg = 0; bg < BPB; ++bg) {
      const uint4* hr = (const uint4*)(const u32*)shp[bg];
      float a0 = biasD + wihj * yv[bg], a1 = 0.f, a2 = 0.f, a3 = 0.f;
      #pragma unroll
      for (int k = 0; k < 16; ++k) {
        uint4 hv = hr[k];
        a0 = dot2h(wpkD[4*k+0], hv.x, a0);
        a1 = dot2h(wpkD[4*k+1], hv.y, a1);
        a2 = dot2h(wpkD[4*k+2], hv.z, a2);
        a3 = dot2h(wpkD[4*k+3], hv.w, a3);
      }
      sg[bg][tid] = (a0 + a1) + (a2 + a3);
    }
    __syncthreads();
    // S7: pointwise LSTM
    if (q4 < BPB) {
      float gi = sigm(sg[q4][hh]);
      float gf = sigm(sg[q4][hh + 128]);
      float gg = tanh_(sg[q4][hh + 256]);
      float go = sigm(sg[q4][hh + 384]);
      float c  = gf * sc[q4][hh] + gi * gg;
      sc[q4][hh] = c;
      float d  = go * tanh_(c);
      sh[q4][hh] = d;
      shp[q4][hh] = f2h(d);
      scp[q4][hh] = f2h(c);
    }
    __syncthreads();
  }

  // ---------- final beta -> ctx -> head ----------
  if (wv < BPB) {                     // wave w computes beta for batch w
    int bg = wv;
    float4 p0 = ((const float4*)spart[bg])[lane];
    float e0 = __expf((p0.x + p0.y) + (p0.z + p0.w));
    float e1 = 0.f;
    if (lane < 36) {
      float4 p1 = ((const float4*)spart[bg])[64 + lane];
      e1 = __expf((p1.x + p1.y) + (p1.z + p1.w));
    }
    float iv = rcpf_(wsum(e0 + e1));
    sye[bg][lane] = e0 * iv;          // overwrite ye with beta
    if (lane < 36) sye[bg][64 + lane] = e1 * iv;
  }
  __syncthreads();
  if (q4 < BPB) {
    const u16* xeb = qws + (size_t)(b0 + q4) * QS + hh;
    float cx = 0.f;
    #pragma unroll 4
    for (int t = 0; t < T_; ++t)
      cx += sye[q4][t] * h2f(xeb[t * NT]);
    su[q4][hh] = cx;                  // ctx
  }
  __syncthreads();
  if (tid < BPB * C_) {
    int bg = tid >> 5, cls = tid & 31;
    const float* w = fcfW + (size_t)cls * 256;
    float acc = fcfb[cls];
    #pragma unroll 8
    for (int k = 0; k < 128; ++k)
      acc += w[k] * sh[bg][k] + w[128 + k] * su[bg][k];
    out[(size_t)(b0 + bg) * C_ + cls] = acc;
  }
}

// ================== fallback (R7 structure, no workspace) ==================
__global__ void __launch_bounds__(NT)
darnn_fb(const float* __restrict__ X,
         const float* __restrict__ eWih, const float* __restrict__ eWhh,
         const float* __restrict__ ebih, const float* __restrict__ ebhh,
         const float* __restrict__ eAw,
         const float* __restrict__ dW1,  const float* __restrict__ db1,
         const float* __restrict__ dW2,
         const float* __restrict__ dWih, const float* __restrict__ dWhh,
         const float* __restrict__ dbih, const float* __restrict__ dbhh,
         const float* __restrict__ fcW,  const float* __restrict__ fcb,
         const float* __restrict__ fcfW, const float* __restrict__ fcfb,
         float* __restrict__ out)
{
  __shared__ __align__(16) u16   sxh[12800];
  __shared__ __align__(16) u16   sXe[12800];
  __shared__ __align__(16) float sg[512];
  __shared__ __align__(16) float sh[128];
  __shared__ __align__(16) float sc[128];
  __shared__ __align__(16) u16   shp[128];
  __shared__ __align__(16) u16   scp[128];
  __shared__ __align__(16) float su[128];
  __shared__ __align__(16) float spart[512];
  __shared__ __align__(16) float sscore[128];
  __shared__ __align__(16) float sctx[128];
  __shared__ float sred[8];
  __shared__ float sredY[2];

  const int tid  = threadIdx.x;
  const int lane = tid & 63;
  const int wv   = tid >> 6;
  const int b    = blockIdx.x;
  const int hh   = tid & 127;
  const int q4   = tid >> 7;

  {
    const float4* Xb4 = (const float4*)(X + (size_t)b * 12800);
    u32* dst = (u32*)sxh;
    #pragma unroll
    for (int i = 0; i < 7; ++i) {
      int idx = tid + NT * i;
      if (idx < 3200) {
        float4 v = Xb4[idx];
        dst[2*idx]   = pkh2(v.x, v.y);
        dst[2*idx+1] = pkh2(v.z, v.w);
      }
    }
  }
  __syncthreads();
  float sval = 0.f;
  if (tid < 128) {
    #pragma unroll 4
    for (int t = 0; t < T_; ++t)
      sval += h2f(sxh[t * 128 + tid]) * eAw[256 + t];
  }
  float ee = (tid < 128) ? __expf(sval) : 0.f;
  float sm = wsum(ee);
  if (lane == 0 && wv < 2) sred[2 + wv] = sm;
  __syncthreads();
  if (tid < 128) {
    su[tid] = ee * rcpf_(sred[2] + sred[3]);
    sh[tid] = 0.f; sc[tid] = 0.f; shp[tid] = 0; scp[tid] = 0;
  }
  __syncthreads();
  {
    u32* sx32 = (u32*)sxh;
    #pragma unroll
    for (int i = 0; i < 13; ++i) {
      int p = tid + NT * i;
      if (p < 6400) {
        float lo, hi; unph(sx32[p], lo, hi);
        int m = (2 * p) & 127;
        sx32[p] = pkh2(lo * su[m], hi * su[m + 1]);
      }
    }
  }
  __syncthreads();

  u32 wpkH[64], wpkI[64];
  {
    const float4* wr = (const float4*)(eWhh + (size_t)tid * 128);
    #pragma unroll
    for (int i = 0; i < 32; ++i) {
      float4 v = wr[i];
      wpkH[2*i] = pkh2(v.x, v.y); wpkH[2*i+1] = pkh2(v.z, v.w);
    }
    const float4* wi = (const float4*)(eWih + (size_t)tid * 128);
    #pragma unroll
    for (int i = 0; i < 32; ++i) {
      float4 v = wi[i];
      wpkI[2*i] = pkh2(v.x, v.y); wpkI[2*i+1] = pkh2(v.z, v.w);
    }
  }
  float biasg = ebih[tid] + ebhh[tid];

  for (int t = 0; t < T_; ++t) {
    float a0 = biasg, a1 = 0.f, a2 = 0.f, a3 = 0.f;
    const uint4* hr = (const uint4*)(const u32*)shp;
    #pragma unroll
    for (int k = 0; k < 16; ++k) {
      uint4 hv = hr[k];
      a0 = dot2h(wpkH[4*k+0], hv.x, a0);
      a1 = dot2h(wpkH[4*k+1], hv.y, a1);
      a2 = dot2h(wpkH[4*k+2], hv.z, a2);
      a3 = dot2h(wpkH[4*k+3], hv.w, a3);
    }
    const uint4* xr = (const uint4*)((const u32*)sxh + t * 64);
    #pragma unroll
    for (int k = 0; k < 16; ++k) {
      uint4 xv = xr[k];
      a0 = dot2h(wpkI[4*k+0], xv.x, a0);
      a1 = dot2h(wpkI[4*k+1], xv.y, a1);
      a2 = dot2h(wpkI[4*k+2], xv.z, a2);
      a3 = dot2h(wpkI[4*k+3], xv.w, a3);
    }
    sg[tid] = (a0 + a1) + (a2 + a3);
    __syncthreads();
    if (tid < 128) {
      float gi = sigm(sg[tid]);
      float gf = sigm(sg[tid + 128]);
      float gg = tanh_(sg[tid + 256]);
      float go = sigm(sg[tid + 384]);
      float c  = gf * sc[tid] + gi * gg;
      sc[tid]  = c;
      float h  = go * tanh_(c);
      sh[tid]  = h;
      u16 hb = f2h(h);
      shp[tid] = hb; scp[tid] = f2h(c);
      sXe[t * 128 + tid] = hb;
    }
    __syncthreads();
  }

  {
    u32 wtp[64];
    const float4* w4 = (const float4*)(dW1 + (size_t)hh * 384 + 256);
    #pragma unroll
    for (int i = 0; i < 32; ++i) {
      float4 v = w4[i];
      wtp[2*i] = pkh2(v.x, v.y); wtp[2*i+1] = pkh2(v.z, v.w);
    }
    float b1v = db1[hh];
    u16 e1out[25];
    #pragma unroll 1
    for (int i = 0; i < 25; ++i) {
      int t = q4 * 25 + i;
      const uint4* xe4 = (const uint4*)(sXe + t * 128);
      float a0 = 0.f, a1 = 0.f;
      #pragma unroll
      for (int k = 0; k < 16; ++k) {
        uint4 xv = xe4[k];
        a0 = dot2h(wtp[4*k+0], xv.x, a0);
        a1 = dot2h(wtp[4*k+1], xv.y, a1);
        a0 = dot2h(wtp[4*k+2], xv.z, a0);
        a1 = dot2h(wtp[4*k+3], xv.w, a1);
      }
      e1out[i] = f2h(a0 + a1 + b1v);
    }
    __syncthreads();
    #pragma unroll 1
    for (int i = 0; i < 25; ++i)
      sxh[(q4 * 25 + i) * 128 + hh] = e1out[i];
  }

  u32 wpkD[64];
  {
    const float4* wr = (const float4*)(dWhh + (size_t)tid * 128);
    #pragma unroll
    for (int i = 0; i < 32; ++i) {
      float4 v = wr[i];
      wpkD[2*i] = pkh2(v.x, v.y); wpkD[2*i+1] = pkh2(v.z, v.w);
    }
  }
  u32 wtpU[32];
  {
    const float4* wu = (const float4*)(dW1 + (size_t)hh * 384 + q4 * 64);
    #pragma unroll
    for (int i = 0; i < 16; ++i) {
      float4 v = wu[i];
      wtpU[2*i] = pkh2(v.x, v.y); wtpU[2*i+1] = pkh2(v.z, v.w);
    }
  }
  float biasD = dbih[tid] + dbhh[tid];
  float wihj  = dWih[tid];
  float w2a   = dW2[lane];
  float w2b   = dW2[lane + 64];
  float fcbv  = fcb[0];
  float fcwv  = (tid < 128) ? fcW[tid] : 0.f;
  if (tid < 128) { sh[tid] = 0.f; sc[tid] = 0.f; shp[tid] = 0; scp[tid] = 0; }
  __syncthreads();

  for (int step = 0; step < T_; ++step) {
    {
      const u32* base = (q4 < 2) ? (const u32*)shp : (const u32*)scp;
      const uint4* vp = (const uint4*)(base + (q4 & 1) * 32);
      float a0 = 0.f, a1 = 0.f;
      #pragma unroll
      for (int k = 0; k < 8; ++k) {
        uint4 v = vp[k];
        a0 = dot2h(wtpU[4*k+0], v.x, a0);
        a1 = dot2h(wtpU[4*k+1], v.y, a1);
        a0 = dot2h(wtpU[4*k+2], v.z, a0);
        a1 = dot2h(wtpU[4*k+3], v.w, a1);
      }
      spart[q4 * 128 + hh] = a0 + a1;
    }
    __syncthreads();
    {
      float ul = spart[lane] + spart[128 + lane]
               + spart[256 + lane] + spart[384 + lane];
      float uh = spart[64 + lane] + spart[192 + lane]
               + spart[320 + lane] + spart[448 + lane];
      #pragma unroll 1
      for (int i = 0; i < 13; ++i) {
        int t = wv + 8 * i;
        if (t < T_) {
          float v = w2a * ptanh(h2f(sxh[t * 128 + lane]) + ul)
                  + w2b * ptanh(h2f(sxh[t * 128 + 64 + lane]) + uh);
          v = wsum(v);
          if (lane == 0) sscore[t] = v;
        }
      }
    }
    __syncthreads();
    if (wv == 0) {
      float s0 = sscore[lane];
      float E0 = __expf(s0);
      float E1v = (lane < 36) ? __expf(sscore[lane + 64]) : 0.f;
      float s  = wsum(E0 + E1v);
      float iv = rcpf_(s);
      sscore[lane] = E0 * iv;
      if (lane < 36) sscore[lane + 64] = E1v * iv;
    }
    __syncthreads();
    {
      float pc = 0.f;
      #pragma unroll
      for (int i = 0; i < 25; ++i) {
        int t = q4 * 25 + i;
        pc += sscore[t] * h2f(sXe[t * 128 + hh]);
      }
      spart[q4 * 128 + hh] = pc;
    }
    __syncthreads();
    {
      float v = 0.f;
      if (tid < 128) {
        float cx = spart[tid] + spart[tid + 128]
                 + spart[tid + 256] + spart[tid + 384];
        sctx[tid] = cx;
        v = fcwv * cx;
      }
      v = wsum(v);
      if (lane == 0 && wv < 2) sredY[wv] = v;
    }
    __syncthreads();
    {
      float yt = sredY[0] + sredY[1] + fcbv;
      float a0 = biasD + wihj * yt, a1 = 0.f, a2 = 0.f, a3 = 0.f;
      const uint4* hr = (const uint4*)(const u32*)shp;
      #pragma unroll
      for (int k = 0; k < 16; ++k) {
        uint4 hv = hr[k];
        a0 = dot2h(wpkD[4*k+0], hv.x, a0);
        a1 = dot2h(wpkD[4*k+1], hv.y, a1);
        a2 = dot2h(wpkD[4*k+2], hv.z, a2);
        a3 = dot2h(wpkD[4*k+3], hv.w, a3);
      }
      sg[tid] = (a0 + a1) + (a2 + a3);
    }
    __syncthreads();
    if (tid < 128) {
      float gi = sigm(sg[tid]);
      float gf = sigm(sg[tid + 128]);
      float gg = tanh_(sg[tid + 256]);
      float go = sigm(sg[tid + 384]);
      float c  = gf * sc[tid] + gi * gg;
      sc[tid]  = c;
      float d  = go * tanh_(c);
      sh[tid]  = d;
      shp[tid] = f2h(d);
      scp[tid] = f2h(c);
    }
    __syncthreads();
  }

  if (tid < C_) {
    float acc = fcfb[tid];
    const float* w = fcfW + (size_t)tid * 256;
    #pragma unroll 8
    for (int k = 0; k < 128; ++k)
      acc += w[k] * sh[k] + w[128 + k] * sctx[k];
    out[(size_t)b * C_ + tid] = acc;
  }
}

extern "C" void kernel_launch(void* const* d_in, const int* in_sizes, int n_in,
                              void* d_out, int out_size, void* d_ws, size_t ws_size,
                              hipStream_t stream) {
  (void)n_in; (void)out_size;
  const float* X    = (const float*)d_in[0];
  const float* eWih = (const float*)d_in[1];
  const float* eWhh = (const float*)d_in[2];
  const float* ebih = (const float*)d_in[3];
  const float* ebhh = (const float*)d_in[4];
  const float* eAw  = (const float*)d_in[5];
  const float* eAb  = (const float*)d_in[6];
  const float* dW1  = (const float*)d_in[7];
  const float* db1  = (const float*)d_in[8];
  const float* dW2  = (const float*)d_in[9];
  const float* db2  = (const float*)d_in[10];
  const float* dWih = (const float*)d_in[11];
  const float* dWhh = (const float*)d_in[12];
  const float* dbih = (const float*)d_in[13];
  const float* dbhh = (const float*)d_in[14];
  const float* fcW  = (const float*)d_in[15];
  const float* fcb  = (const float*)d_in[16];
  const float* fcfW = (const float*)d_in[17];
  const float* fcfb = (const float*)d_in[18];
  float* out = (float*)d_out;

  const int B = in_sizes[0] / (T_ * 128);
  const size_t needQ = (size_t)B * QS * sizeof(u16);
  if (ws_size >= needQ && (B % BPB) == 0) {
    darnn4<<<dim3(B / BPB), dim3(NT), 0, stream>>>(
        X, eWih, eWhh, ebih, ebhh, eAw, eAb,
        dW1, db1, dW2, db2, dWih, dWhh, dbih, dbhh,
        fcW, fcb, fcfW, fcfb, (u16*)d_ws, out);
  } else {
    darnn_fb<<<dim3(B), dim3(NT), 0, stream>>>(
        X, eWih, eWhh, ebih, ebhh, eAw,
        dW1, db1, dW2, dWih, dWhh, dbih, dbhh,
        fcW, fcb, fcfW, fcfb, out);
  }
}

// Round 2
// 1407.137 us; speedup vs baseline: 1.0691x; 1.0691x over previous
//
#include <hip/hip_runtime.h>

// DA-RNN fused — R10: fix R9's spill regression.
//  * R9 post-mortem: __launch_bounds__(512,4) second arg acts as min BLOCKS/CU
//    on this toolchain (VGPR_Count dropped to 64 = 32-waves/CU cap), spilling
//    the persistent weight arrays (wpkD[64]+wtpU[32] ~ 96 regs) -> 2.4 GB of
//    scratch traffic/launch, VALUBusy 57->48. Occupancy thesis never tested.
//  * R10: __launch_bounds__(512,2) -> VGPR cap 128 (R8's proven allocation,
//    zero spills) while LDS 67 KB still admits 2 blocks/CU (16 waves).
//  * Everything else identical to R9 (BPB=2, grid 512).

typedef unsigned int   u32;
typedef unsigned short u16;

#define T_  100
#define C_  32
#define NT  512
#define BPB 2
#define TS  132
#define QS  (T_ * NT)

typedef __attribute__((ext_vector_type(2))) __fp16 h16x2;

#if __has_builtin(__builtin_amdgcn_fdot2)
#define HAVE_FDOT2 1
#else
#define HAVE_FDOT2 0
#endif

__device__ __forceinline__ u32 pkh2(float a, float b) {
#if __has_builtin(__builtin_amdgcn_cvt_pkrtz)
  h16x2 p = __builtin_amdgcn_cvt_pkrtz(a, b);
  return __builtin_bit_cast(u32, p);
#else
  union { __fp16 h[2]; u32 u; } v;
  v.h[0] = (__fp16)a; v.h[1] = (__fp16)b;
  return v.u;
#endif
}
__device__ __forceinline__ void unph(u32 p, float& lo, float& hi) {
  union { u32 u; __fp16 h[2]; } v; v.u = p;
  lo = (float)v.h[0]; hi = (float)v.h[1];
}
__device__ __forceinline__ u16 f2h(float f) {
  union { __fp16 h; u16 u; } v; v.h = (__fp16)f; return v.u;
}
__device__ __forceinline__ float h2f(u16 u) {
  union { u16 u; __fp16 h; } v; v.u = u; return (float)v.h;
}
__device__ __forceinline__ float dot2h(u32 w, u32 x, float acc) {
#if HAVE_FDOT2
  return __builtin_amdgcn_fdot2(__builtin_bit_cast(h16x2, w),
                                __builtin_bit_cast(h16x2, x),
                                acc, false);
#else
  float a, b, c, d;
  unph(w, a, b); unph(x, c, d);
  return fmaf(a, c, fmaf(b, d, acc));
#endif
}

#if __has_builtin(__builtin_amdgcn_rcpf)
__device__ __forceinline__ float rcpf_(float x){ return __builtin_amdgcn_rcpf(x); }
#else
__device__ __forceinline__ float rcpf_(float x){ return 1.0f / x; }
#endif
__device__ __forceinline__ float sigm(float x){ return rcpf_(1.0f + __expf(-x)); }
__device__ __forceinline__ float tanh_(float x){
  return 1.0f - 2.0f * rcpf_(1.0f + __expf(2.0f * x));
}
__device__ __forceinline__ float ptanh(float x){
  x = fminf(1.0f, fmaxf(-1.0f, x));
  float x2 = x * x;
  float p  = fmaf(x2, 0.1333333f, -0.3333333f);
  return x * fmaf(x2, p, 1.0f);
}
__device__ __forceinline__ float wsum(float v){
  #pragma unroll
  for (int o = 32; o; o >>= 1) v += __shfl_xor(v, o, 64);
  return v;
}

// ============================ fast kernel (2 batches/block) =================
__global__ void __launch_bounds__(NT, 2)
darnn4(const float* __restrict__ X,
       const float* __restrict__ eWih, const float* __restrict__ eWhh,
       const float* __restrict__ ebih, const float* __restrict__ ebhh,
       const float* __restrict__ eAw,  const float* __restrict__ eAb,
       const float* __restrict__ dW1,  const float* __restrict__ db1,
       const float* __restrict__ dW2,  const float* __restrict__ db2,
       const float* __restrict__ dWih, const float* __restrict__ dWhh,
       const float* __restrict__ dbih, const float* __restrict__ dbhh,
       const float* __restrict__ fcW,  const float* __restrict__ fcb,
       const float* __restrict__ fcfW, const float* __restrict__ fcfb,
       u16* __restrict__ qws,
       float* __restrict__ out)
{
  // LDS ~66.7 KB -> 2 blocks/CU
  __shared__ __align__(16) u16   sE1[BPB][T_ * TS];  // x_tilde -> E1    52800
  __shared__ __align__(16) float sg[BPB][512];       //                  4096
  __shared__ __align__(16) float sh[BPB][128];       // h/d fp32         1024
  __shared__ __align__(16) float sc[BPB][128];       // c fp32           1024
  __shared__ __align__(16) u16   shp[BPB][128];      // h/d fp16          512
  __shared__ __align__(16) u16   scp[BPB][128];      // c fp16            512
  __shared__ __align__(16) float su[BPB][128];       // u / ctx          1024
  __shared__ __align__(16) float spart[BPB][512];    // partials         4096
  __shared__ __align__(16) float sye[BPB][128];      // ye -> beta       1024
  __shared__ __align__(16) float sw2[128];           //                   512
  __shared__ float sred[16];

  const int tid  = threadIdx.x;
  const int lane = tid & 63;
  const int wv   = tid >> 6;     // 0..7
  const int hh   = tid & 127;
  const int q4   = tid >> 7;     // 0..3 (batch idx when <BPB, else col-quarter)
  const int b0   = blockIdx.x * BPB;

  (void)eAb; (void)db2;          // cancel under softmax shift-invariance

  if (tid < 128) sw2[tid] = dW2[tid];

  // ---------- alpha (no max-sub; h/c terms cancel) + x_tilde ----------
  {
    const float* xp = X + (size_t)(b0 + (q4 & (BPB - 1))) * 12800 + hh;
    if (q4 < BPB) {
      float sval = 0.f;
      #pragma unroll 4
      for (int t = 0; t < T_; ++t) sval += xp[t * 128] * eAw[256 + t];
      float e = __expf(sval);
      float s = wsum(e);
      if (lane == 0) sred[wv] = s;
      // stash e across the barrier via spart (cheap, avoids recompute)
      spart[q4][hh] = e;
    }
    __syncthreads();
    if (q4 < BPB) {
      float e  = spart[q4][hh];
      float al = e * rcpf_(sred[q4 * 2] + sred[q4 * 2 + 1]);
      #pragma unroll 4
      for (int t = 0; t < T_; ++t)
        sE1[q4][t * TS + hh] = f2h(al * xp[t * 128]);
      sh[q4][hh] = 0.f; sc[q4][hh] = 0.f; shp[q4][hh] = 0; scp[q4][hh] = 0;
    }
  }
  __syncthreads();

  // ---------- Q GEMM: Q[b][t][r] = eWih[r,:]·x_tilde  (self-produced) ----
  {
    u32 wq[64];
    const float4* wi = (const float4*)(eWih + (size_t)tid * 128);
    #pragma unroll
    for (int i = 0; i < 32; ++i) {
      float4 v = wi[i];
      wq[2*i]   = pkh2(v.x, v.y);
      wq[2*i+1] = pkh2(v.z, v.w);
    }
    #pragma unroll 1
    for (int bg = 0; bg < BPB; ++bg) {
      u16* qb = qws + (size_t)(b0 + bg) * QS;
      #pragma unroll 1
      for (int t = 0; t < T_; ++t) {
        const uint2* xr = (const uint2*)(&sE1[bg][t * TS]);
        float a0 = 0.f, a1 = 0.f;
        #pragma unroll
        for (int k = 0; k < 16; ++k) {
          uint2 xv = xr[k];
          a0 = dot2h(wq[2*k],   xv.x, a0);
          a1 = dot2h(wq[2*k+1], xv.y, a1);
        }
        qb[t * NT + tid] = f2h(a0 + a1);
      }
    }
  }

  // ---------- encoder (2 barriers/step) ----------
  {
    u32 wpkH[64];
    const float4* wr = (const float4*)(eWhh + (size_t)tid * 128);
    #pragma unroll
    for (int i = 0; i < 32; ++i) {
      float4 v = wr[i];
      wpkH[2*i]   = pkh2(v.x, v.y);
      wpkH[2*i+1] = pkh2(v.z, v.w);
    }
    float biasg = ebih[tid] + ebhh[tid];

    u16 qc[BPB];
    #pragma unroll
    for (int bg = 0; bg < BPB; ++bg)
      qc[bg] = qws[(size_t)(b0 + bg) * QS + tid];

    for (int t = 0; t < T_; ++t) {
      u16 qn[BPB];
      #pragma unroll
      for (int bg = 0; bg < BPB; ++bg)
        qn[bg] = (t + 1 < T_) ? qws[(size_t)(b0 + bg) * QS + (t + 1) * NT + tid]
                              : (u16)0;
      #pragma unroll 1
      for (int bg = 0; bg < BPB; ++bg) {
        const uint4* hr = (const uint4*)(const u32*)shp[bg];
        float a0 = biasg + h2f(qc[bg]), a1 = 0.f, a2 = 0.f, a3 = 0.f;
        #pragma unroll
        for (int k = 0; k < 16; ++k) {
          uint4 hv = hr[k];
          a0 = dot2h(wpkH[4*k+0], hv.x, a0);
          a1 = dot2h(wpkH[4*k+1], hv.y, a1);
          a2 = dot2h(wpkH[4*k+2], hv.z, a2);
          a3 = dot2h(wpkH[4*k+3], hv.w, a3);
        }
        sg[bg][tid] = (a0 + a1) + (a2 + a3);
      }
      __syncthreads();
      if (q4 < BPB) {
        float gi = sigm(sg[q4][hh]);
        float gf = sigm(sg[q4][hh + 128]);
        float gg = tanh_(sg[q4][hh + 256]);
        float go = sigm(sg[q4][hh + 384]);
        float c  = gf * sc[q4][hh] + gi * gg;
        sc[q4][hh] = c;
        float h  = go * tanh_(c);
        sh[q4][hh] = h;
        u16 hb = f2h(h);
        shp[q4][hh] = hb;
        scp[q4][hh] = f2h(c);
        // Xe row t shares Q's slab (Q[t] already consumed; barrier-ordered)
        qws[(size_t)(b0 + q4) * QS + t * NT + hh] = hb;
      }
      __syncthreads();
      #pragma unroll
      for (int bg = 0; bg < BPB; ++bg) qc[bg] = qn[bg];
    }
  }

  // ---------- ye[t] = fcW · Xe[t]  ----------
  if (hh < T_) {
    #pragma unroll 1
    for (int bg = 0; bg < BPB; ++bg) {
      const uint2* xe = (const uint2*)(qws + (size_t)(b0 + bg) * QS
                                       + hh * NT + q4 * 32);
      const float* fw = fcW + q4 * 32;
      float a = 0.f;
      #pragma unroll
      for (int k = 0; k < 8; ++k) {
        uint2 xv = xe[k];
        float l0, l1, l2, l3;
        unph(xv.x, l0, l1); unph(xv.y, l2, l3);
        a += fw[4*k]*l0 + fw[4*k+1]*l1 + fw[4*k+2]*l2 + fw[4*k+3]*l3;
      }
      spart[bg][hh * 4 + q4] = a;
    }
  }
  __syncthreads();
  if (hh < T_ && q4 < BPB) {
    float4 p = ((const float4*)spart[q4])[hh];
    sye[q4][hh] = (p.x + p.y) + (p.z + p.w);
  }
  __syncthreads();

  // ---------- E1[t][h] = dW1[h][256:384]·Xe[t] + db1[h] -> LDS ----------
  {
    u32 wtp[64];
    const float4* w4p = (const float4*)(dW1 + (size_t)hh * 384 + 256);
    #pragma unroll
    for (int i = 0; i < 32; ++i) {
      float4 v = w4p[i];
      wtp[2*i]   = pkh2(v.x, v.y);
      wtp[2*i+1] = pkh2(v.z, v.w);
    }
    float b1v = db1[hh];
    #pragma unroll 1
    for (int bg = 0; bg < BPB; ++bg) {
      #pragma unroll 1
      for (int i = 0; i < 25; ++i) {
        int t = q4 * 25 + i;
        const uint2* xe = (const uint2*)(qws + (size_t)(b0 + bg) * QS + t * NT);
        float a0 = 0.f, a1 = 0.f;
        #pragma unroll
        for (int k = 0; k < 16; ++k) {
          uint2 xv = xe[k];
          a0 = dot2h(wtp[2*k],   xv.x, a0);
          a1 = dot2h(wtp[2*k+1], xv.y, a1);
        }
        sE1[bg][t * TS + hh] = f2h(a0 + a1 + b1v);
      }
    }
  }

  // ---------- decoder weights ----------
  u32 wpkD[64];
  {
    const float4* wr = (const float4*)(dWhh + (size_t)tid * 128);
    #pragma unroll
    for (int i = 0; i < 32; ++i) {
      float4 v = wr[i];
      wpkD[2*i]   = pkh2(v.x, v.y);
      wpkD[2*i+1] = pkh2(v.z, v.w);
    }
  }
  u32 wtpU[32];   // dW1 row hh, z-cols [q4*64, q4*64+64)
  {
    const float4* wu = (const float4*)(dW1 + (size_t)hh * 384 + q4 * 64);
    #pragma unroll
    for (int i = 0; i < 16; ++i) {
      float4 v = wu[i];
      wtpU[2*i]   = pkh2(v.x, v.y);
      wtpU[2*i+1] = pkh2(v.z, v.w);
    }
  }
  float biasD = dbih[tid] + dbhh[tid];
  float wihj  = dWih[tid];
  float fcbv  = fcb[0];
  if (q4 < BPB) {
    sh[q4][hh] = 0.f; sc[q4][hh] = 0.f; shp[q4][hh] = 0; scp[q4][hh] = 0;
  }
  __syncthreads();

  // ---------- decoder (5 barriers/step) ----------
  for (int step = 0; step < T_; ++step) {
    // S0: u partials over z=[d;c] cols q4*64..+64, all batches
    #pragma unroll 1
    for (int bg = 0; bg < BPB; ++bg) {
      const u32* bs = (q4 < 2) ? (const u32*)shp[bg] : (const u32*)scp[bg];
      const uint4* vp = (const uint4*)(bs + (q4 & 1) * 32);
      float a0 = 0.f, a1 = 0.f;
      #pragma unroll
      for (int k = 0; k < 8; ++k) {
        uint4 v = vp[k];
        a0 = dot2h(wtpU[4*k+0], v.x, a0);
        a1 = dot2h(wtpU[4*k+1], v.y, a1);
        a0 = dot2h(wtpU[4*k+2], v.z, a0);
        a1 = dot2h(wtpU[4*k+3], v.w, a1);
      }
      spart[bg][q4 * 128 + hh] = a0 + a1;
    }
    __syncthreads();
    // S1: reduce u
    if (q4 < BPB)
      su[q4][hh] = spart[q4][hh] + spart[q4][128 + hh]
                 + spart[q4][256 + hh] + spart[q4][384 + hh];
    __syncthreads();
    // S2: score partials: thread (t=hh<100, quad q4), 32 h each
    if (hh < T_) {
      #pragma unroll 1
      for (int bg = 0; bg < BPB; ++bg) {
        const uint2*  ep = (const uint2*)(&sE1[bg][hh * TS + q4 * 32]);
        const float4* up = (const float4*)(&su[bg][q4 * 32]);
        const float4* wp = (const float4*)(&sw2[q4 * 32]);
        float acc = 0.f;
        #pragma unroll
        for (int j = 0; j < 8; ++j) {
          uint2  e2 = ep[j];
          float4 u4 = up[j];
          float4 w4 = wp[j];
          float e0, e1, e2f, e3;
          unph(e2.x, e0, e1); unph(e2.y, e2f, e3);
          acc += w4.x * ptanh(e0  + u4.x) + w4.y * ptanh(e1 + u4.y)
               + w4.z * ptanh(e2f + u4.z) + w4.w * ptanh(e3 + u4.w);
        }
        spart[bg][hh * 4 + q4] = acc;
      }
    }
    __syncthreads();
    // S3: softmax over t + y, wave-redundant (no barrier after)
    float yv[BPB];
    #pragma unroll
    for (int bg = 0; bg < BPB; ++bg) {
      float4 p0 = ((const float4*)spart[bg])[lane];
      float e0 = __expf((p0.x + p0.y) + (p0.z + p0.w));
      float es = e0, ys = e0 * sye[bg][lane];
      if (lane < 36) {
        float4 p1 = ((const float4*)spart[bg])[64 + lane];
        float e1 = __expf((p1.x + p1.y) + (p1.z + p1.w));
        es += e1; ys += e1 * sye[bg][64 + lane];
      }
      es = wsum(es); ys = wsum(ys);
      yv[bg] = ys * rcpf_(es) + fcbv;
    }
    // S6: gates
    #pragma unroll 1
    for (int bg = 0; bg < BPB; ++bg) {
      const uint4* hr = (const uint4*)(const u32*)shp[bg];
      float a0 = biasD + wihj * yv[bg], a1 = 0.f, a2 = 0.f, a3 = 0.f;
      #pragma unroll
      for (int k = 0; k < 16; ++k) {
        uint4 hv = hr[k];
        a0 = dot2h(wpkD[4*k+0], hv.x, a0);
        a1 = dot2h(wpkD[4*k+1], hv.y, a1);
        a2 = dot2h(wpkD[4*k+2], hv.z, a2);
        a3 = dot2h(wpkD[4*k+3], hv.w, a3);
      }
      sg[bg][tid] = (a0 + a1) + (a2 + a3);
    }
    __syncthreads();
    // S7: pointwise LSTM
    if (q4 < BPB) {
      float gi = sigm(sg[q4][hh]);
      float gf = sigm(sg[q4][hh + 128]);
      float gg = tanh_(sg[q4][hh + 256]);
      float go = sigm(sg[q4][hh + 384]);
      float c  = gf * sc[q4][hh] + gi * gg;
      sc[q4][hh] = c;
      float d  = go * tanh_(c);
      sh[q4][hh] = d;
      shp[q4][hh] = f2h(d);
      scp[q4][hh] = f2h(c);
    }
    __syncthreads();
  }

  // ---------- final beta -> ctx -> head ----------
  if (wv < BPB) {                     // wave w computes beta for batch w
    int bg = wv;
    float4 p0 = ((const float4*)spart[bg])[lane];
    float e0 = __expf((p0.x + p0.y) + (p0.z + p0.w));
    float e1 = 0.f;
    if (lane < 36) {
      float4 p1 = ((const float4*)spart[bg])[64 + lane];
      e1 = __expf((p1.x + p1.y) + (p1.z + p1.w));
    }
    float iv = rcpf_(wsum(e0 + e1));
    sye[bg][lane] = e0 * iv;          // overwrite ye with beta
    if (lane < 36) sye[bg][64 + lane] = e1 * iv;
  }
  __syncthreads();
  if (q4 < BPB) {
    const u16* xeb = qws + (size_t)(b0 + q4) * QS + hh;
    float cx = 0.f;
    #pragma unroll 4
    for (int t = 0; t < T_; ++t)
      cx += sye[q4][t] * h2f(xeb[t * NT]);
    su[q4][hh] = cx;                  // ctx
  }
  __syncthreads();
  if (tid < BPB * C_) {
    int bg = tid >> 5, cls = tid & 31;
    const float* w = fcfW + (size_t)cls * 256;
    float acc = fcfb[cls];
    #pragma unroll 8
    for (int k = 0; k < 128; ++k)
      acc += w[k] * sh[bg][k] + w[128 + k] * su[bg][k];
    out[(size_t)(b0 + bg) * C_ + cls] = acc;
  }
}

// ================== fallback (R7 structure, no workspace) ==================
__global__ void __launch_bounds__(NT)
darnn_fb(const float* __restrict__ X,
         const float* __restrict__ eWih, const float* __restrict__ eWhh,
         const float* __restrict__ ebih, const float* __restrict__ ebhh,
         const float* __restrict__ eAw,
         const float* __restrict__ dW1,  const float* __restrict__ db1,
         const float* __restrict__ dW2,
         const float* __restrict__ dWih, const float* __restrict__ dWhh,
         const float* __restrict__ dbih, const float* __restrict__ dbhh,
         const float* __restrict__ fcW,  const float* __restrict__ fcb,
         const float* __restrict__ fcfW, const float* __restrict__ fcfb,
         float* __restrict__ out)
{
  __shared__ __align__(16) u16   sxh[12800];
  __shared__ __align__(16) u16   sXe[12800];
  __shared__ __align__(16) float sg[512];
  __shared__ __align__(16) float sh[128];
  __shared__ __align__(16) float sc[128];
  __shared__ __align__(16) u16   shp[128];
  __shared__ __align__(16) u16   scp[128];
  __shared__ __align__(16) float su[128];
  __shared__ __align__(16) float spart[512];
  __shared__ __align__(16) float sscore[128];
  __shared__ __align__(16) float sctx[128];
  __shared__ float sred[8];
  __shared__ float sredY[2];

  const int tid  = threadIdx.x;
  const int lane = tid & 63;
  const int wv   = tid >> 6;
  const int b    = blockIdx.x;
  const int hh   = tid & 127;
  const int q4   = tid >> 7;

  {
    const float4* Xb4 = (const float4*)(X + (size_t)b * 12800);
    u32* dst = (u32*)sxh;
    #pragma unroll
    for (int i = 0; i < 7; ++i) {
      int idx = tid + NT * i;
      if (idx < 3200) {
        float4 v = Xb4[idx];
        dst[2*idx]   = pkh2(v.x, v.y);
        dst[2*idx+1] = pkh2(v.z, v.w);
      }
    }
  }
  __syncthreads();
  float sval = 0.f;
  if (tid < 128) {
    #pragma unroll 4
    for (int t = 0; t < T_; ++t)
      sval += h2f(sxh[t * 128 + tid]) * eAw[256 + t];
  }
  float ee = (tid < 128) ? __expf(sval) : 0.f;
  float sm = wsum(ee);
  if (lane == 0 && wv < 2) sred[2 + wv] = sm;
  __syncthreads();
  if (tid < 128) {
    su[tid] = ee * rcpf_(sred[2] + sred[3]);
    sh[tid] = 0.f; sc[tid] = 0.f; shp[tid] = 0; scp[tid] = 0;
  }
  __syncthreads();
  {
    u32* sx32 = (u32*)sxh;
    #pragma unroll
    for (int i = 0; i < 13; ++i) {
      int p = tid + NT * i;
      if (p < 6400) {
        float lo, hi; unph(sx32[p], lo, hi);
        int m = (2 * p) & 127;
        sx32[p] = pkh2(lo * su[m], hi * su[m + 1]);
      }
    }
  }
  __syncthreads();

  u32 wpkH[64], wpkI[64];
  {
    const float4* wr = (const float4*)(eWhh + (size_t)tid * 128);
    #pragma unroll
    for (int i = 0; i < 32; ++i) {
      float4 v = wr[i];
      wpkH[2*i] = pkh2(v.x, v.y); wpkH[2*i+1] = pkh2(v.z, v.w);
    }
    const float4* wi = (const float4*)(eWih + (size_t)tid * 128);
    #pragma unroll
    for (int i = 0; i < 32; ++i) {
      float4 v = wi[i];
      wpkI[2*i] = pkh2(v.x, v.y); wpkI[2*i+1] = pkh2(v.z, v.w);
    }
  }
  float biasg = ebih[tid] + ebhh[tid];

  for (int t = 0; t < T_; ++t) {
    float a0 = biasg, a1 = 0.f, a2 = 0.f, a3 = 0.f;
    const uint4* hr = (const uint4*)(const u32*)shp;
    #pragma unroll
    for (int k = 0; k < 16; ++k) {
      uint4 hv = hr[k];
      a0 = dot2h(wpkH[4*k+0], hv.x, a0);
      a1 = dot2h(wpkH[4*k+1], hv.y, a1);
      a2 = dot2h(wpkH[4*k+2], hv.z, a2);
      a3 = dot2h(wpkH[4*k+3], hv.w, a3);
    }
    const uint4* xr = (const uint4*)((const u32*)sxh + t * 64);
    #pragma unroll
    for (int k = 0; k < 16; ++k) {
      uint4 xv = xr[k];
      a0 = dot2h(wpkI[4*k+0], xv.x, a0);
      a1 = dot2h(wpkI[4*k+1], xv.y, a1);
      a2 = dot2h(wpkI[4*k+2], xv.z, a2);
      a3 = dot2h(wpkI[4*k+3], xv.w, a3);
    }
    sg[tid] = (a0 + a1) + (a2 + a3);
    __syncthreads();
    if (tid < 128) {
      float gi = sigm(sg[tid]);
      float gf = sigm(sg[tid + 128]);
      float gg = tanh_(sg[tid + 256]);
      float go = sigm(sg[tid + 384]);
      float c  = gf * sc[tid] + gi * gg;
      sc[tid]  = c;
      float h  = go * tanh_(c);
      sh[tid]  = h;
      u16 hb = f2h(h);
      shp[tid] = hb; scp[tid] = f2h(c);
      sXe[t * 128 + tid] = hb;
    }
    __syncthreads();
  }

  {
    u32 wtp[64];
    const float4* w4 = (const float4*)(dW1 + (size_t)hh * 384 + 256);
    #pragma unroll
    for (int i = 0; i < 32; ++i) {
      float4 v = w4[i];
      wtp[2*i] = pkh2(v.x, v.y); wtp[2*i+1] = pkh2(v.z, v.w);
    }
    float b1v = db1[hh];
    u16 e1out[25];
    #pragma unroll 1
    for (int i = 0; i < 25; ++i) {
      int t = q4 * 25 + i;
      const uint4* xe4 = (const uint4*)(sXe + t * 128);
      float a0 = 0.f, a1 = 0.f;
      #pragma unroll
      for (int k = 0; k < 16; ++k) {
        uint4 xv = xe4[k];
        a0 = dot2h(wtp[4*k+0], xv.x, a0);
        a1 = dot2h(wtp[4*k+1], xv.y, a1);
        a0 = dot2h(wtp[4*k+2], xv.z, a0);
        a1 = dot2h(wtp[4*k+3], xv.w, a1);
      }
      e1out[i] = f2h(a0 + a1 + b1v);
    }
    __syncthreads();
    #pragma unroll 1
    for (int i = 0; i < 25; ++i)
      sxh[(q4 * 25 + i) * 128 + hh] = e1out[i];
  }

  u32 wpkD[64];
  {
    const float4* wr = (const float4*)(dWhh + (size_t)tid * 128);
    #pragma unroll
    for (int i = 0; i < 32; ++i) {
      float4 v = wr[i];
      wpkD[2*i] = pkh2(v.x, v.y); wpkD[2*i+1] = pkh2(v.z, v.w);
    }
  }
  u32 wtpU[32];
  {
    const float4* wu = (const float4*)(dW1 + (size_t)hh * 384 + q4 * 64);
    #pragma unroll
    for (int i = 0; i < 16; ++i) {
      float4 v = wu[i];
      wtpU[2*i] = pkh2(v.x, v.y); wtpU[2*i+1] = pkh2(v.z, v.w);
    }
  }
  float biasD = dbih[tid] + dbhh[tid];
  float wihj  = dWih[tid];
  float w2a   = dW2[lane];
  float w2b   = dW2[lane + 64];
  float fcbv  = fcb[0];
  float fcwv  = (tid < 128) ? fcW[tid] : 0.f;
  if (tid < 128) { sh[tid] = 0.f; sc[tid] = 0.f; shp[tid] = 0; scp[tid] = 0; }
  __syncthreads();

  for (int step = 0; step < T_; ++step) {
    {
      const u32* base = (q4 < 2) ? (const u32*)shp : (const u32*)scp;
      const uint4* vp = (const uint4*)(base + (q4 & 1) * 32);
      float a0 = 0.f, a1 = 0.f;
      #pragma unroll
      for (int k = 0; k < 8; ++k) {
        uint4 v = vp[k];
        a0 = dot2h(wtpU[4*k+0], v.x, a0);
        a1 = dot2h(wtpU[4*k+1], v.y, a1);
        a0 = dot2h(wtpU[4*k+2], v.z, a0);
        a1 = dot2h(wtpU[4*k+3], v.w, a1);
      }
      spart[q4 * 128 + hh] = a0 + a1;
    }
    __syncthreads();
    {
      float ul = spart[lane] + spart[128 + lane]
               + spart[256 + lane] + spart[384 + lane];
      float uh = spart[64 + lane] + spart[192 + lane]
               + spart[320 + lane] + spart[448 + lane];
      #pragma unroll 1
      for (int i = 0; i < 13; ++i) {
        int t = wv + 8 * i;
        if (t < T_) {
          float v = w2a * ptanh(h2f(sxh[t * 128 + lane]) + ul)
                  + w2b * ptanh(h2f(sxh[t * 128 + 64 + lane]) + uh);
          v = wsum(v);
          if (lane == 0) sscore[t] = v;
        }
      }
    }
    __syncthreads();
    if (wv == 0) {
      float s0 = sscore[lane];
      float E0 = __expf(s0);
      float E1v = (lane < 36) ? __expf(sscore[lane + 64]) : 0.f;
      float s  = wsum(E0 + E1v);
      float iv = rcpf_(s);
      sscore[lane] = E0 * iv;
      if (lane < 36) sscore[lane + 64] = E1v * iv;
    }
    __syncthreads();
    {
      float pc = 0.f;
      #pragma unroll
      for (int i = 0; i < 25; ++i) {
        int t = q4 * 25 + i;
        pc += sscore[t] * h2f(sXe[t * 128 + hh]);
      }
      spart[q4 * 128 + hh] = pc;
    }
    __syncthreads();
    {
      float v = 0.f;
      if (tid < 128) {
        float cx = spart[tid] + spart[tid + 128]
                 + spart[tid + 256] + spart[tid + 384];
        sctx[tid] = cx;
        v = fcwv * cx;
      }
      v = wsum(v);
      if (lane == 0 && wv < 2) sredY[wv] = v;
    }
    __syncthreads();
    {
      float yt = sredY[0] + sredY[1] + fcbv;
      float a0 = biasD + wihj * yt, a1 = 0.f, a2 = 0.f, a3 = 0.f;
      const uint4* hr = (const uint4*)(const u32*)shp;
      #pragma unroll
      for (int k = 0; k < 16; ++k) {
        uint4 hv = hr[k];
        a0 = dot2h(wpkD[4*k+0], hv.x, a0);
        a1 = dot2h(wpkD[4*k+1], hv.y, a1);
        a2 = dot2h(wpkD[4*k+2], hv.z, a2);
        a3 = dot2h(wpkD[4*k+3], hv.w, a3);
      }
      sg[tid] = (a0 + a1) + (a2 + a3);
    }
    __syncthreads();
    if (tid < 128) {
      float gi = sigm(sg[tid]);
      float gf = sigm(sg[tid + 128]);
      float gg = tanh_(sg[tid + 256]);
      float go = sigm(sg[tid + 384]);
      float c  = gf * sc[tid] + gi * gg;
      sc[tid]  = c;
      float d  = go * tanh_(c);
      sh[tid]  = d;
      shp[tid] = f2h(d);
      scp[tid] = f2h(c);
    }
    __syncthreads();
  }

  if (tid < C_) {
    float acc = fcfb[tid];
    const float* w = fcfW + (size_t)tid * 256;
    #pragma unroll 8
    for (int k = 0; k < 128; ++k)
      acc += w[k] * sh[k] + w[128 + k] * sctx[k];
    out[(size_t)b * C_ + tid] = acc;
  }
}

extern "C" void kernel_launch(void* const* d_in, const int* in_sizes, int n_in,
                              void* d_out, int out_size, void* d_ws, size_t ws_size,
                              hipStream_t stream) {
  (void)n_in; (void)out_size;
  const float* X    = (const float*)d_in[0];
  const float* eWih = (const float*)d_in[1];
  const float* eWhh = (const float*)d_in[2];
  const float* ebih = (const float*)d_in[3];
  const float* ebhh = (const float*)d_in[4];
  const float* eAw  = (const float*)d_in[5];
  const float* eAb  = (const float*)d_in[6];
  const float* dW1  = (const float*)d_in[7];
  const float* db1  = (const float*)d_in[8];
  const float* dW2  = (const float*)d_in[9];
  const float* db2  = (const float*)d_in[10];
  const float* dWih = (const float*)d_in[11];
  const float* dWhh = (const float*)d_in[12];
  const float* dbih = (const float*)d_in[13];
  const float* dbhh = (const float*)d_in[14];
  const float* fcW  = (const float*)d_in[15];
  const float* fcb  = (const float*)d_in[16];
  const float* fcfW = (const float*)d_in[17];
  const float* fcfb = (const float*)d_in[18];
  float* out = (float*)d_out;

  const int B = in_sizes[0] / (T_ * 128);
  const size_t needQ = (size_t)B * QS * sizeof(u16);
  if (ws_size >= needQ && (B % BPB) == 0) {
    darnn4<<<dim3(B / BPB), dim3(NT), 0, stream>>>(
        X, eWih, eWhh, ebih, ebhh, eAw, eAb,
        dW1, db1, dW2, db2, dWih, dWhh, dbih, dbhh,
        fcW, fcb, fcfW, fcfb, (u16*)d_ws, out);
  } else {
    darnn_fb<<<dim3(B), dim3(NT), 0, stream>>>(
        X, eWih, eWhh, ebih, ebhh, eAw,
        dW1, db1, dW2, dWih, dWhh, dbih, dbhh,
        fcW, fcb, fcfW, fcfb, out);
  }
}